// Round 7
// baseline (119.359 us; speedup 1.0000x reference)
//
#include <hip/hip_runtime.h>

// Reference-exact fp32 d2: no FMA contraction. d2 = (sqn+sqm) + dot' with
// dot' built from (-2x) pre-scaled m-points is bit-identical to the ref's
// (sqn+sqm) - 2*dot (power-of-2 scaling / negation commute with rounding).
// Self-distance: dt(n,n) = -2*sq_n exactly, so d2(n,n) == 0 exactly.
// v_pk_mul_f32 / v_pk_add_f32 are per-component IEEE f32 mul/add -> packed
// evaluation of two m's is bit-identical to the scalar sequence.
#pragma clang fp contract(off)

#define NBATCH 256   // B*L
#define NPTS   512   // points per batch
#define JDIM   128   // logit dim
#define NPAIR  (NBATCH * NPTS)   // 131072

typedef float f32x2 __attribute__((ext_vector_type(2)));

// Direct HBM->LDS DMA, 16B per lane. LDS dest is wave-uniform base; lane l
// lands at base + l*16. tile[q*512 + t] (float4) order == base + lane*16
// for base = tile + q*512 + (t & ~63).  (verified bit-exact in rounds 2/4)
__device__ __forceinline__ void gload_lds16(const void* g, void* l) {
    __builtin_amdgcn_global_load_lds(
        (const __attribute__((address_space(1))) void*)g,
        (__attribute__((address_space(3))) void*)l, 16, 0, 0);
}

// ---------------- K1: packed-pair argmax / masked-argmin --------------------
// 1024 blocks x 512 threads (quarter-batch per block) -> 4 blocks/CU x 8
// waves = 32 waves/CU. Lanes 4g..4g+3 own point p; each scans one m-quarter
// as 64 float2 PAIRS: arithmetic via v_pk_* (2 m's per instr, bit-identical
// per component), selects scalar lo-then-hi (ascending first-occurrence).
// Then the r6-verified 2-stage __shfl_xor butterfly merges quarters (strict
// compares keep the lower m-range on ties) == full ascending scan.
// LDS: quarter-skewed SoA, quarter stride 260 float2 -> the 4 quarters' b64
// reads land in 4 disjoint 2-bank groups (conflict-free, 16-lane broadcast).
__global__ __launch_bounds__(512) void argmm_kernel(
    const float* __restrict__ xyz,   // [NBATCH, NPTS, 3]
    int* __restrict__ pmax,          // [NBATCH*NPTS]
    int* __restrict__ pmin)          // [NBATCH*NPTS]
{
    __shared__ f32x2 soa[4 * 260 + 4];   // [q]{x[64],y[64],z[64],sq[64]} ~8.3 KB

    const int t  = threadIdx.x;              // 0..511
    const int bl = blockIdx.x >> 2;          // batch
    const int qq = blockIdx.x & 3;           // point-quarter of this block
    const float* xp = xyz + (size_t)bl * NPTS * 3;

    // stage all 512 points, scaled, into packed SoA; sq in ref order
    {
        float x = xp[3 * t], y = xp[3 * t + 1], z = xp[3 * t + 2];
        float sq = (x * x + y * y) + z * z;  // matches np.sum(x*x,-1)
        int q = t >> 7, j = (t & 127) >> 1, hf = t & 1;
        float* b = (float*)&soa[q * 260 + j];
        b[hf]       = -2.0f * x;             // X at float2 offset   0
        b[128 + hf] = -2.0f * y;             // Y at float2 offset  64
        b[256 + hf] = -2.0f * z;             // Z at float2 offset 128
        b[384 + hf] = sq;                    // W at float2 offset 192
    }

    // own point raw from global (r5-verified): p = qq*128 + (t>>2)
    const int p = qq * 128 + (t >> 2);       // point owned by this 4-lane group
    const int q = t & 3;                     // this lane's m-quarter
    float ox = xp[3 * p], oy = xp[3 * p + 1], oz = xp[3 * p + 2];
    float oq = (ox * ox + oy * oy) + oz * oz;
    __syncthreads();

    const f32x2 ox2 = {ox, ox}, oy2 = {oy, oy}, oz2 = {oz, oz}, oq2 = {oq, oq};
    const f32x2* Xp = &soa[q * 260 +   0];
    const f32x2* Yp = &soa[q * 260 +  64];
    const f32x2* Zp = &soa[q * 260 + 128];
    const f32x2* Wp = &soa[q * 260 + 192];

    const int m0 = q << 7;
    float bmax = -1.0f, bmin = 3.0e38f;
    int   ima  = m0,    imi  = m0;
    #pragma unroll 8
    for (int j = 0; j < 64; ++j) {
        f32x2 px = Xp[j], py = Yp[j], pz = Zp[j], pw = Wp[j];
        f32x2 t1, t2, t3, s, dt, da, d2;
        // (ox*px + oy*py) + oz*pz  and  (oq + pw) + dt — exact ref order,
        // two m's per instruction, per-component rounding == scalar.
        asm("v_pk_mul_f32 %0, %1, %2" : "=v"(t1) : "v"(ox2), "v"(px));
        asm("v_pk_mul_f32 %0, %1, %2" : "=v"(t2) : "v"(oy2), "v"(py));
        asm("v_pk_add_f32 %0, %1, %2" : "=v"(s)  : "v"(t1),  "v"(t2));
        asm("v_pk_mul_f32 %0, %1, %2" : "=v"(t3) : "v"(oz2), "v"(pz));
        asm("v_pk_add_f32 %0, %1, %2" : "=v"(dt) : "v"(s),   "v"(t3));
        asm("v_pk_add_f32 %0, %1, %2" : "=v"(da) : "v"(oq2), "v"(pw));
        asm("v_pk_add_f32 %0, %1, %2" : "=v"(d2) : "v"(da),  "v"(dt));

        const int m = m0 + 2 * j;
        {   // lo half = m  (processed first: ascending first-occurrence)
            float d = d2.x;
            bool gt = d > bmax;  ima = gt ? m : ima;  bmax = gt ? d : bmax;
            bool lt = (d < bmin) && (d > 0.0f);       // fold d2==0 self mask
            imi = lt ? m : imi;  bmin = lt ? d : bmin;
        }
        {   // hi half = m+1
            float d = d2.y;  const int m1 = m + 1;
            bool gt = d > bmax;  ima = gt ? m1 : ima;  bmax = gt ? d : bmax;
            bool lt = (d < bmin) && (d > 0.0f);
            imi = lt ? m1 : imi; bmin = lt ? d : bmin;
        }
    }

    // 2-stage butterfly over the aligned 4-lane group (r6-verified).
    // Quarters ascend with lane; strict compares keep the LOWER range on ties
    // at every stage -> global first-occurrence, matching the full scan.
    #pragma unroll
    for (int st = 1; st <= 2; st <<= 1) {
        float obmax = __shfl_xor(bmax, st); int oima = __shfl_xor(ima, st);
        float obmin = __shfl_xor(bmin, st); int oimi = __shfl_xor(imi, st);
        bool hi = (t & st) != 0;             // my range is the upper of the pair
        float lmax = hi ? obmax : bmax;  int lima = hi ? oima : ima;
        float hmax = hi ? bmax : obmax;  int hima = hi ? ima  : oima;
        bool w = hmax > lmax;
        bmax = w ? hmax : lmax;  ima = w ? hima : lima;
        float lmin = hi ? obmin : bmin;  int limi = hi ? oimi : imi;
        float hmin = hi ? bmin : obmin;  int himi = hi ? imi  : oimi;
        bool x2 = hmin < lmin;
        bmin = x2 ? hmin : lmin;  imi = x2 ? himi : limi;
    }

    if (q == 0)      pmax[bl * NPTS + p] = ima;
    else if (q == 1) pmin[bl * NPTS + p] = imi;
}

// ---------------- K2: sim gathers, DMA-staged (compute == round-0) ----------
// Grid 2048 = 256 batches x 8 chunks of 16 ypred rows. Staging now goes
// through global_load_lds width=16 (no VGPR round trip, ~8 fewer wave-instrs
// per thread); tile layout and the entire compute/reduce path are
// byte-identical to the verified round-0 kernel -> partials bit-identical.
__global__ __launch_bounds__(512) void sim_kernel(
    const float* __restrict__ ypred,   // [NBATCH, JDIM, NPTS]
    const int* __restrict__ pmax,
    const int* __restrict__ pmin,
    float* __restrict__ partials)      // [2048]
{
    __shared__ __align__(16) float L[16 * NPTS];   // 32 KB tile
    __shared__ float wred[8];

    const int t  = threadIdx.x;
    const int bl = blockIdx.x >> 3;
    const int c  = blockIdx.x & 7;     // j-chunk
    const int wbase = t & ~63;         // wave-uniform DMA dest base

    const float4* src = (const float4*)(ypred + (size_t)bl * JDIM * NPTS
                                              + (size_t)c * 16 * NPTS);
    #pragma unroll
    for (int qd = 0; qd < 4; ++qd)
        gload_lds16(src + qd * 512 + t, (float4*)L + qd * 512 + wbase);

    // partner indices: issued after the DMA, land alongside it
    const int pma = pmax[bl * NPTS + t];
    const int pmi = pmin[bl * NPTS + t];

    asm volatile("s_waitcnt vmcnt(0)" ::: "memory");
    __syncthreads();

    float accP = 0.0f, accM = 0.0f;
    #pragma unroll
    for (int r = 0; r < 16; ++r) {
        float a  = L[r * NPTS + t];      // stride-1, conflict-free
        float b  = L[r * NPTS + pma];    // random gather
        float cm = L[r * NPTS + pmi];
        accP = fmaf(a, b, accP);
        accM = fmaf(a, cm, accM);
    }

    float d = accP - accM;
    #pragma unroll
    for (int off = 32; off > 0; off >>= 1)
        d += __shfl_down(d, off);
    if ((t & 63) == 0) wred[t >> 6] = d;
    __syncthreads();
    if (t == 0) {
        float ssum = 0.0f;
        #pragma unroll
        for (int w = 0; w < 8; ++w) ssum += wred[w];
        partials[blockIdx.x] = ssum;
    }
}

// ---------------- K3: final mean over 2048 partials (verbatim round-0) ------
__global__ __launch_bounds__(1024) void reduce_mean_kernel(
    const float* __restrict__ partials, float* __restrict__ out)
{
    const int t = threadIdx.x;
    float v = partials[t] + partials[t + 1024];
    #pragma unroll
    for (int off = 32; off > 0; off >>= 1)
        v += __shfl_down(v, off);

    __shared__ float w[16];
    if ((t & 63) == 0) w[t >> 6] = v;
    __syncthreads();
    if (t == 0) {
        float s = 0.0f;
        #pragma unroll
        for (int i = 0; i < 16; ++i) s += w[i];
        out[0] = s * (1.0f / (float)NPAIR);
    }
}

extern "C" void kernel_launch(void* const* d_in, const int* in_sizes, int n_in,
                              void* d_out, int out_size, void* d_ws, size_t ws_size,
                              hipStream_t stream) {
    const float* ypred = (const float*)d_in[0];   // [8,32,128,512] f32
    const float* xyz   = (const float*)d_in[1];   // [8,32,512,3]  f32

    // ws: pmax[131072] ints, pmin[131072] ints, partials[2048] floats (~1.06 MB)
    int*   pmax     = (int*)d_ws;
    int*   pmin     = pmax + NPAIR;
    float* partials = (float*)(pmin + NPAIR);
    float* out      = (float*)d_out;

    argmm_kernel<<<4 * NBATCH, 512, 0, stream>>>(xyz, pmax, pmin);
    sim_kernel<<<8 * NBATCH, 512, 0, stream>>>(ypred, pmax, pmin, partials);
    reduce_mean_kernel<<<1, 1024, 0, stream>>>(partials, out);
}

// Round 8
// 119.123 us; speedup vs baseline: 1.0020x; 1.0020x over previous
//
#include <hip/hip_runtime.h>

// Reference-exact fp32 d2: no FMA contraction. d2 = (sqn+sqm) + dot' with
// dot' built from (-2x) pre-scaled m-points is bit-identical to the ref's
// (sqn+sqm) - 2*dot (power-of-2 scaling / negation commute with rounding).
// Self-distance: dt(n,n) = -2*sq_n exactly, so d2(n,n) == 0 exactly.
#pragma clang fp contract(off)

#define NBATCH 256   // B*L
#define NPTS   512   // points per batch
#define JDIM   128   // logit dim
#define NPAIR  (NBATCH * NPTS)   // 131072

// Direct HBM->LDS DMA, 16B per lane. LDS dest is wave-uniform base; lane l
// lands at base + l*16. tile[q*512 + t] (float4) order == base + lane*16
// for base = tile + q*512 + (t & ~63).  (verified bit-exact in r2/r4/r7)
__device__ __forceinline__ void gload_lds16(const void* g, void* l) {
    __builtin_amdgcn_global_load_lds(
        (const __attribute__((address_space(1))) void*)g,
        (__attribute__((address_space(3))) void*)l, 16, 0, 0);
}

// ---------------- K1: 4 lanes/point, shfl-merged argmax / masked-argmin -----
// (verbatim from round 6 — best-measured K1; issue-floor-bound at 32 waves/CU)
__global__ __launch_bounds__(512) void argmm_kernel(
    const float* __restrict__ xyz,   // [NBATCH, NPTS, 3]
    int* __restrict__ pmax,          // [NBATCH*NPTS]
    int* __restrict__ pmin)          // [NBATCH*NPTS]
{
    __shared__ float4 xyzS[NPTS + 4];        // skewed: phys = m + (m>>7)

    const int t  = threadIdx.x;              // 0..511
    const int bl = blockIdx.x >> 2;          // batch
    const int qq = blockIdx.x & 3;           // point-quarter of this block
    const float* xp = xyz + (size_t)bl * NPTS * 3;

    // stage all 512 points, scaled; sq computed in ref order from raw values
    {
        float x = xp[3 * t], y = xp[3 * t + 1], z = xp[3 * t + 2];
        float sq = (x * x + y * y) + z * z;  // matches np.sum(x*x,-1)
        xyzS[t + (t >> 7)] = make_float4(-2.0f * x, -2.0f * y, -2.0f * z, sq);
    }
    __syncthreads();

    const int p = qq * 128 + (t >> 2);       // point owned by this 4-lane group
    const int q = t & 3;                     // this lane's m-quarter

    // raw own coords recovered exactly: -0.5f * (-2x) == x (pow-2 scaling)
    float4 ov = xyzS[p + (p >> 7)];
    float ox = -0.5f * ov.x, oy = -0.5f * ov.y, oz = -0.5f * ov.z;
    float oq_ = ov.w;

    const float4* xb = &xyzS[q];             // +q == the quarter's skew
    const int m0 = q << 7;
    float bmax = -1.0f, bmin = 3.0e38f;
    int   ima  = m0,    imi  = m0;
    #pragma unroll 8
    for (int mm = 0; mm < 128; ++mm) {
        int m = m0 + mm;
        float4 qv = xb[m];                   // phys m+q == m+(m>>7) in-quarter
        float dt = (ox * qv.x + oy * qv.y) + oz * qv.z;   // == -2*dot, exact
        float d2 = (oq_ + qv.w) + dt;        // bits == ref d2 (pre-clamp)
        bool gt = d2 > bmax;                 // strict -> first occurrence
        ima = gt ? m : ima;  bmax = gt ? d2 : bmax;
        bool lt = (d2 < bmin) && (d2 > 0.0f);   // fold the d2==0 self/dupe mask
        imi = lt ? m : imi;  bmin = lt ? d2 : bmin;
    }

    // 2-stage butterfly over the aligned 4-lane group (in-wave, no barrier).
    // Quarters ascend with lane; strict compares keep the LOWER range on ties
    // at every stage -> global first-occurrence, matching the verified merge.
    #pragma unroll
    for (int st = 1; st <= 2; st <<= 1) {
        float obmax = __shfl_xor(bmax, st); int oima = __shfl_xor(ima, st);
        float obmin = __shfl_xor(bmin, st); int oimi = __shfl_xor(imi, st);
        bool hi = (t & st) != 0;             // my range is the upper of the pair
        float lmax = hi ? obmax : bmax;  int lima = hi ? oima : ima;
        float hmax = hi ? bmax : obmax;  int hima = hi ? ima  : oima;
        bool w = hmax > lmax;
        bmax = w ? hmax : lmax;  ima = w ? hima : lima;
        float lmin = hi ? obmin : bmin;  int limi = hi ? oimi : imi;
        float hmin = hi ? bmin : obmin;  int himi = hi ? imi  : oimi;
        bool x2 = hmin < lmin;
        bmin = x2 ? hmin : lmin;  imi = x2 ? himi : limi;
    }

    if (q == 0)      pmax[bl * NPTS + p] = ima;
    else if (q == 1) pmin[bl * NPTS + p] = imi;
}

// ---------------- K2: chunk-pipelined sim gathers ---------------------------
// Grid 512 = 256 batches x 2 halves; block (bl,h) owns chunks 4h..4h+3 (ypred
// still read exactly ONCE chip-wide). Two 32 KB DMA tiles, depth-1 prefetch,
// counted vmcnt(4) in the main loop (never drain), raw s_barriers: HBM stream
// stays saturated across chunk boundaries; every thread computes.
// LDS 65.6 KB -> exactly 2 independent blocks/CU (no 1-block convoy).
// Per-chunk compute/reduce is byte-identical to the verified round-0 path and
// writes partials[bl*8 + h*4 + i] -> partials bit-identical, K3 unchanged.
__global__ __launch_bounds__(512) void sim_kernel(
    const float* __restrict__ ypred,   // [NBATCH, JDIM, NPTS]
    const int* __restrict__ pmax,
    const int* __restrict__ pmin,
    float* __restrict__ partials)      // [2048]
{
    __shared__ __align__(16) float Lt[2][16 * NPTS];   // 64 KB
    __shared__ float wred[8];

    const int t  = threadIdx.x;
    const int bl = blockIdx.x >> 1;
    const int h  = blockIdx.x & 1;     // chunk-half
    const int wbase = t & ~63;         // wave-uniform DMA dest base

    const float4* src = (const float4*)(ypred + (size_t)bl * JDIM * NPTS
                                              + (size_t)h * 4 * 16 * NPTS);

    // own partner indices (same for all 4 chunks) — issue first
    const int pma = pmax[bl * NPTS + t];
    const int pmi = pmin[bl * NPTS + t];

    // issue local chunks 0 and 1 into buf0, buf1 (8 DMA loads in flight)
    #pragma unroll
    for (int qd = 0; qd < 4; ++qd)
        gload_lds16(src + qd * 512 + t, (float4*)Lt[0] + qd * 512 + wbase);
    #pragma unroll
    for (int qd = 0; qd < 4; ++qd)
        gload_lds16(src + 2048 + qd * 512 + t,
                    (float4*)Lt[1] + qd * 512 + wbase);

    #pragma unroll
    for (int i = 0; i < 4; ++i) {
        // chunk i's 4 loads are the oldest outstanding; keep newest 4 in
        // flight (i<3). Last iteration has nothing behind it -> drain.
        if (i < 3) asm volatile("s_waitcnt vmcnt(4)" ::: "memory");
        else       asm volatile("s_waitcnt vmcnt(0)" ::: "memory");
        __builtin_amdgcn_s_barrier();          // chunk i landed block-wide

        // compute chunk i — bit-exact replica of the round-0 per-chunk path
        const float* L = Lt[i & 1];
        float accP = 0.0f, accM = 0.0f;
        #pragma unroll
        for (int r = 0; r < 16; ++r) {
            float a  = L[r * NPTS + t];      // stride-1, conflict-free
            float b  = L[r * NPTS + pma];    // random gather
            float cm = L[r * NPTS + pmi];
            accP = fmaf(a, b, accP);
            accM = fmaf(a, cm, accM);
        }
        float d = accP - accM;
        #pragma unroll
        for (int off = 32; off > 0; off >>= 1)
            d += __shfl_down(d, off);
        if ((t & 63) == 0) wred[t >> 6] = d;

        // wred visible + all waves done reading Lt[i&1]; does NOT drain vmcnt
        asm volatile("s_waitcnt lgkmcnt(0)" ::: "memory");
        __builtin_amdgcn_s_barrier();

        if (i + 2 < 4) {                     // refill freed buffer, chunk i+2
            #pragma unroll
            for (int qd = 0; qd < 4; ++qd)
                gload_lds16(src + (i + 2) * 2048 + qd * 512 + t,
                            (float4*)Lt[i & 1] + qd * 512 + wbase);
        }
        if (t == 0) {                        // fold in the original w order
            float ssum = 0.0f;
            #pragma unroll
            for (int w = 0; w < 8; ++w) ssum += wred[w];
            partials[bl * 8 + h * 4 + i] = ssum;   // same bits as round-0
        }
        // t0's wred read races nothing: next wred writes happen only after
        // the next top-of-loop barrier, which t0 must also reach.
    }
}

// ---------------- K3: final mean over 2048 partials (verbatim round-0) ------
__global__ __launch_bounds__(1024) void reduce_mean_kernel(
    const float* __restrict__ partials, float* __restrict__ out)
{
    const int t = threadIdx.x;
    float v = partials[t] + partials[t + 1024];
    #pragma unroll
    for (int off = 32; off > 0; off >>= 1)
        v += __shfl_down(v, off);

    __shared__ float w[16];
    if ((t & 63) == 0) w[t >> 6] = v;
    __syncthreads();
    if (t == 0) {
        float s = 0.0f;
        #pragma unroll
        for (int i = 0; i < 16; ++i) s += w[i];
        out[0] = s * (1.0f / (float)NPAIR);
    }
}

extern "C" void kernel_launch(void* const* d_in, const int* in_sizes, int n_in,
                              void* d_out, int out_size, void* d_ws, size_t ws_size,
                              hipStream_t stream) {
    const float* ypred = (const float*)d_in[0];   // [8,32,128,512] f32
    const float* xyz   = (const float*)d_in[1];   // [8,32,512,3]  f32

    // ws: pmax[131072] ints, pmin[131072] ints, partials[2048] floats (~1.06 MB)
    int*   pmax     = (int*)d_ws;
    int*   pmin     = pmax + NPAIR;
    float* partials = (float*)(pmin + NPAIR);
    float* out      = (float*)d_out;

    argmm_kernel<<<4 * NBATCH, 512, 0, stream>>>(xyz, pmax, pmin);
    sim_kernel<<<2 * NBATCH, 512, 0, stream>>>(ypred, pmax, pmin, partials);
    reduce_mean_kernel<<<1, 1024, 0, stream>>>(partials, out);
}

// Round 9
// 116.497 us; speedup vs baseline: 1.0246x; 1.0225x over previous
//
#include <hip/hip_runtime.h>

// Reference-exact fp32 d2: no FMA contraction. d2 = (sqn+sqm) + dot' with
// dot' built from (-2x) pre-scaled m-points is bit-identical to the ref's
// (sqn+sqm) - 2*dot (power-of-2 scaling / negation commute with rounding).
// Self-distance: dt(n,n) = -2*sq_n exactly, so d2(n,n) == 0 exactly.
#pragma clang fp contract(off)

#define NBATCH 256   // B*L
#define NPTS   512   // points per batch
#define JDIM   128   // logit dim
#define NPAIR  (NBATCH * NPTS)   // 131072

// ---------------- K1: per-point argmax / masked-argmin of d2 ----------------
// Grid 1024 = 4 blocks/batch (128 points each). Block 512 thr, 40 KB LDS ->
// 4 blocks/CU, 32 waves. Thread t: point-group g = t&31 (4 pts), m-subrange
// s = t>>5 (32 m's). One 2-address LDS broadcast read feeds 4 d2's.
__global__ __launch_bounds__(512) void argmm_kernel(
    const float* __restrict__ xyz,   // [NBATCH, NPTS, 3]
    int* __restrict__ pmax,          // [NBATCH*NPTS]
    int* __restrict__ pmin)          // [NBATCH*NPTS]
{
    __shared__ float4 xyzS[NPTS];            // scaled (-2x,-2y,-2z, sq) : 8 KB
    __shared__ float mv[16][128];  __shared__ int mi[16][128];   // 16 KB
    __shared__ float nv[16][128];  __shared__ int ni[16][128];   // 16 KB

    const int t  = threadIdx.x;
    const int bl = blockIdx.x >> 2;
    const int qq = blockIdx.x & 3;           // point-quarter of this block
    const float* xp = xyz + (size_t)bl * NPTS * 3;

    // stage all 512 points, scaled; sq computed in ref order from raw values
    {
        float x = xp[3 * t], y = xp[3 * t + 1], z = xp[3 * t + 2];
        float sq = (x * x + y * y) + z * z;  // matches np.sum(x*x,-1)
        xyzS[t] = make_float4(-2.0f * x, -2.0f * y, -2.0f * z, sq);
    }

    // own 4 points raw from global: 12 consecutive floats = 3 float4
    const int g = t & 31, s = t >> 5;
    const int pbase = qq * 128 + g * 4;
    float ox[4], oy[4], oz[4], oq[4];
    {
        const float4* own = (const float4*)(xp + 3 * pbase);
        float4 o0 = own[0], o1 = own[1], o2 = own[2];
        ox[0] = o0.x; oy[0] = o0.y; oz[0] = o0.z;
        ox[1] = o0.w; oy[1] = o1.x; oz[1] = o1.y;
        ox[2] = o1.z; oy[2] = o1.w; oz[2] = o2.x;
        ox[3] = o2.y; oy[3] = o2.z; oz[3] = o2.w;
        #pragma unroll
        for (int k = 0; k < 4; ++k)
            oq[k] = (ox[k] * ox[k] + oy[k] * oy[k]) + oz[k] * oz[k];
    }
    __syncthreads();

    const int mbase = s * 32;
    float bmax[4], bmin[4]; int ima[4], imi[4];
    #pragma unroll
    for (int k = 0; k < 4; ++k) {
        bmax[k] = -1.0f; bmin[k] = 3.0e38f; ima[k] = mbase; imi[k] = mbase;
    }

    #pragma unroll 8
    for (int mm = 0; mm < 32; ++mm) {
        int m = mbase + mm;
        float4 qv = xyzS[m];                 // 2 addrs/wave -> free broadcast
        #pragma unroll
        for (int k = 0; k < 4; ++k) {
            float dt = (ox[k] * qv.x + oy[k] * qv.y) + oz[k] * qv.z; // == -2*dot
            float d2 = (oq[k] + qv.w) + dt;  // bits == ref d2 (pre-clamp)
            bool gt = d2 > bmax[k];          // strict -> first occurrence
            ima[k] = gt ? m : ima[k];  bmax[k] = gt ? d2 : bmax[k];
            // ref masks clamp(d2)==0 <=> d2<=0; fold into the compare
            bool lt = (d2 < bmin[k]) && (d2 > 0.0f);
            imi[k] = lt ? m : imi[k];  bmin[k] = lt ? d2 : bmin[k];
        }
    }

    #pragma unroll
    for (int k = 0; k < 4; ++k) {
        int pt = g * 4 + k;
        mv[s][pt] = bmax[k];  mi[s][pt] = ima[k];
        nv[s][pt] = bmin[k];  ni[s][pt] = imi[k];
    }
    __syncthreads();

    // merge 16 ascending-m subranges; strict compare keeps lowest m-range on
    // exact ties -> first-occurrence. 128 threads max, 128 threads min.
    if (t < 256) {
        const int pt = t & 127;
        const int out_idx = bl * NPTS + qq * 128 + pt;
        if (t < 128) {
            float bv = mv[0][pt]; int bi = mi[0][pt];
            #pragma unroll
            for (int ss = 1; ss < 16; ++ss) {
                float v = mv[ss][pt]; int i = mi[ss][pt];
                bool w = v > bv; bi = w ? i : bi; bv = w ? v : bv;
            }
            pmax[out_idx] = bi;
        } else {
            float sv = nv[0][pt]; int si = ni[0][pt];
            #pragma unroll
            for (int ss = 1; ss < 16; ++ss) {
                float u = nv[ss][pt]; int j = ni[ss][pt];
                bool x = u < sv; si = x ? j : si; sv = x ? u : sv;
            }
            pmin[out_idx] = si;
        }
    }
}

// ---------------- K2: sim gathers, j-chunked, one barrier per block --------
// Grid 2048 = 256 batches x 8 chunks of 16 ypred rows. Block 512 thr: thread
// t owns point n=t; reads a once, gathers both partners. ypred read exactly
// once from HBM chip-wide -> streaming-bound.
__global__ __launch_bounds__(512) void sim_kernel(
    const float* __restrict__ ypred,   // [NBATCH, JDIM, NPTS]
    const int* __restrict__ pmax,
    const int* __restrict__ pmin,
    float* __restrict__ partials)      // [2048]
{
    __shared__ float L[16 * NPTS];     // 32 KB tile
    __shared__ float wred[8];

    const int t  = threadIdx.x;
    const int bl = blockIdx.x >> 3;
    const int c  = blockIdx.x & 7;     // j-chunk

    // partner indices: issue early, land under the staging loads
    const int pma = pmax[bl * NPTS + t];
    const int pmi = pmin[bl * NPTS + t];

    const float4* src = (const float4*)(ypred + (size_t)bl * JDIM * NPTS
                                              + (size_t)c * 16 * NPTS);
    float4 v0 = src[t], v1 = src[512 + t], v2 = src[1024 + t], v3 = src[1536 + t];
    float4* dst = (float4*)L;
    dst[t] = v0;  dst[512 + t] = v1;  dst[1024 + t] = v2;  dst[1536 + t] = v3;
    __syncthreads();

    float accP = 0.0f, accM = 0.0f;
    #pragma unroll
    for (int r = 0; r < 16; ++r) {
        float a  = L[r * NPTS + t];      // stride-1, conflict-free
        float b  = L[r * NPTS + pma];    // random gather, ~2-way (free)
        float cm = L[r * NPTS + pmi];
        accP = fmaf(a, b, accP);
        accM = fmaf(a, cm, accM);
    }

    float d = accP - accM;
    #pragma unroll
    for (int off = 32; off > 0; off >>= 1)
        d += __shfl_down(d, off);
    if ((t & 63) == 0) wred[t >> 6] = d;
    __syncthreads();
    if (t == 0) {
        float ssum = 0.0f;
        #pragma unroll
        for (int w = 0; w < 8; ++w) ssum += wred[w];
        partials[blockIdx.x] = ssum;
    }
}

// ---------------- K3: final mean over 2048 partials -------------------------
__global__ __launch_bounds__(1024) void reduce_mean_kernel(
    const float* __restrict__ partials, float* __restrict__ out)
{
    const int t = threadIdx.x;
    float v = partials[t] + partials[t + 1024];
    #pragma unroll
    for (int off = 32; off > 0; off >>= 1)
        v += __shfl_down(v, off);

    __shared__ float w[16];
    if ((t & 63) == 0) w[t >> 6] = v;
    __syncthreads();
    if (t == 0) {
        float s = 0.0f;
        #pragma unroll
        for (int i = 0; i < 16; ++i) s += w[i];
        out[0] = s * (1.0f / (float)NPAIR);
    }
}

extern "C" void kernel_launch(void* const* d_in, const int* in_sizes, int n_in,
                              void* d_out, int out_size, void* d_ws, size_t ws_size,
                              hipStream_t stream) {
    const float* ypred = (const float*)d_in[0];   // [8,32,128,512] f32
    const float* xyz   = (const float*)d_in[1];   // [8,32,512,3]  f32

    // ws: pmax[131072] ints, pmin[131072] ints, partials[2048] floats (~1.06 MB)
    int*   pmax     = (int*)d_ws;
    int*   pmin     = pmax + NPAIR;
    float* partials = (float*)(pmin + NPAIR);
    float* out      = (float*)d_out;

    argmm_kernel<<<4 * NBATCH, 512, 0, stream>>>(xyz, pmax, pmin);
    sim_kernel<<<8 * NBATCH, 512, 0, stream>>>(ypred, pmax, pmin, partials);
    reduce_mean_kernel<<<1, 1024, 0, stream>>>(partials, out);
}